// Round 5
// baseline (2014.464 us; speedup 1.0000x reference)
//
#include <hip/hip_runtime.h>

typedef __bf16 bf16x8 __attribute__((ext_vector_type(8)));
typedef __bf16 bf16x4 __attribute__((ext_vector_type(4)));
typedef float  f32x4  __attribute__((ext_vector_type(4)));

#define GAMMA 0.99f

__device__ __forceinline__ void gload_lds16(const void* g, void* l) {
  __builtin_amdgcn_global_load_lds(
      (const __attribute__((address_space(1))) void*)g,
      (__attribute__((address_space(3))) void*)l, 16, 0, 0);
}

#define VMCNT0() asm volatile("s_waitcnt vmcnt(0)" ::: "memory")
#define BAR() __builtin_amdgcn_s_barrier()
#define MFMA(d, a, b) d = __builtin_amdgcn_mfma_f32_16x16x32_bf16(a, b, d, 0, 0, 0)

// ------------------------------------------------- mega: scan + converts ----
// block 0            : discounted-return scan (1024 threads)
// blocks 1..nObs     : obs fp32 -> bf16 streaming convert
// blocks nObs+1..+512: W1/W2 transpose+cvt -> BT1/BT2 (4 subtiles per block)
__global__ __launch_bounds__(1024) void mega_prep(
    const float* __restrict__ rw, float* __restrict__ G,
    const float* __restrict__ obs, __bf16* __restrict__ obsb,
    const float* __restrict__ W1, const float* __restrict__ W2,
    __bf16* __restrict__ BT1, __bf16* __restrict__ BT2, int nObs) {
  __shared__ float smem[4224];
  const int blk = blockIdx.x;
  const int t = threadIdx.x;
  if (blk == 0) {
    // ---- scan ----
    float* sv = smem;
    const float4* rp = (const float4*)(rw + t * 64);
    float4 lv[16];
#pragma unroll
    for (int i = 0; i < 16; ++i) lv[i] = rp[i];
    float loc[64];
#pragma unroll
    for (int i = 0; i < 16; ++i) {
      loc[4 * i + 0] = lv[i].x; loc[4 * i + 1] = lv[i].y;
      loc[4 * i + 2] = lv[i].z; loc[4 * i + 3] = lv[i].w;
    }
    float g = 0.f;
#pragma unroll
    for (int j = 63; j >= 0; --j) { g = loc[j] + GAMMA * g; loc[j] = g; }
    sv[t] = g;
    float W = GAMMA;
#pragma unroll
    for (int i = 0; i < 6; ++i) W *= W;  // gamma^64
    float v = g;
    for (int s = 1; s < 1024; s <<= 1) {
      __syncthreads();
      float o = (t + s < 1024) ? sv[t + s] : 0.f;
      __syncthreads();
      v += W * o;
      sv[t] = v;
      W *= W;
    }
    __syncthreads();
    const float nxt = (t < 1023) ? sv[t + 1] : 0.f;
    float pw = GAMMA;
#pragma unroll
    for (int j = 63; j >= 0; --j) {
      G[t * 64 + j] = loc[j] + pw * nxt;
      pw *= GAMMA;
    }
  } else if (blk <= nObs) {
    // ---- obs convert: 32768 elems per block ----
    const size_t base = (size_t)(blk - 1) * 32768 + (size_t)t * 8;
#pragma unroll
    for (int it = 0; it < 4; ++it) {
      const size_t e = base + (size_t)it * 8192;
      float4 u0 = *(const float4*)(obs + e);
      float4 u1 = *(const float4*)(obs + e + 4);
      bf16x8 o = {(__bf16)u0.x, (__bf16)u0.y, (__bf16)u0.z, (__bf16)u0.w,
                  (__bf16)u1.x, (__bf16)u1.y, (__bf16)u1.z, (__bf16)u1.w};
      *(bf16x8*)(obsb + e) = o;
    }
  } else {
    // ---- W transpose+cvt: 4 subtiles of 32x32 per block ----
    const int sub = t >> 8, tt = t & 255;
    const int wi = (blk - nObs - 1) * 4 + sub;  // 0..2047
    const float* W = (wi >= 1024) ? W2 : W1;
    __bf16* O = (wi >= 1024) ? BT2 : BT1;
    const int tile = wi & 1023;
    const int ti = tile >> 5, tj = tile & 31;
    float* s = smem + sub * 1056;  // [32][33]
    const int rr = tt >> 3, c4 = (tt & 7) * 4;
    float4 v = *(const float4*)(W + (size_t)(ti * 32 + rr) * 1024 + tj * 32 + c4);
    s[rr * 33 + c4 + 0] = v.x; s[rr * 33 + c4 + 1] = v.y;
    s[rr * 33 + c4 + 2] = v.z; s[rr * 33 + c4 + 3] = v.w;
    __syncthreads();
    bf16x4 o = {(__bf16)s[(c4 + 0) * 33 + rr], (__bf16)s[(c4 + 1) * 33 + rr],
                (__bf16)s[(c4 + 2) * 33 + rr], (__bf16)s[(c4 + 3) * 33 + rr]};
    *(bf16x4*)(O + (size_t)(tj * 32 + rr) * 1024 + ti * 32 + c4) = o;
  }
}

// ---------------------------------------------------------------------------
// GEMM: BM=BN=256, BK=32, 512 threads = 8 waves (wsr 2 x wsc 4), 2 blocks/CU.
// LDS 64 KB: buf{0,1} x { A [256r][32k] , B [256n][32k] } bf16, 64-B rows.
// Row r holds 4 16-B chunks; global chunk g stored at slot g ^ ((r>>1)&3)
// (conflict-free for both the linear gload_lds staging and the frag reads).
// One barrier + one vmcnt(0) per K-tile; cross-block overlap hides drains.
// ---------------------------------------------------------------------------
#define GEMM_KLOOP(APTR, BPTR)                                                 \
  extern __shared__ char lds[];                                                \
  const int t = threadIdx.x, lane = t & 63, w = t >> 6;                        \
  const int wsr = w >> 2, wsc = w & 3, g = lane >> 4, l15 = lane & 15;         \
  const int bid = blockIdx.x;                                                  \
  const int mb = (bid & 7) * 32 + ((bid >> 3) >> 2);                           \
  const int nb = (bid >> 3) & 3;                                               \
  const size_t stg_off =                                                       \
      (size_t)(t >> 2) * 2048 + (size_t)(((t & 3) ^ ((t >> 3) & 3)) * 16);     \
  const char* Ag = (const char*)(APTR) + (size_t)mb * 524288 + stg_off;        \
  const char* Bg = (const char*)(BPTR) + (size_t)nb * 524288 + stg_off;        \
  const int csw = (g ^ ((l15 >> 1) & 3)) << 4;                                 \
  const int arb = (wsr * 64 + l15) * 64 + csw;                                 \
  const int brb = (wsc * 32 + l15) * 64 + csw + 16384;                         \
  f32x4 acc[2][4][2][2];                                                       \
  const f32x4 zero = {0.f, 0.f, 0.f, 0.f};                                     \
  _Pragma("unroll") for (int a_ = 0; a_ < 2; ++a_)                             \
  _Pragma("unroll") for (int b_ = 0; b_ < 4; ++b_)                             \
  _Pragma("unroll") for (int c_ = 0; c_ < 2; ++c_)                             \
  _Pragma("unroll") for (int d_ = 0; d_ < 2; ++d_)                             \
    acc[a_][b_][c_][d_] = zero;                                                \
  auto STA = [&](int buf, int kt) {                                            \
    const char* s = Ag + kt * 64;                                              \
    char* d = lds + buf * 32768 + t * 16;                                      \
    gload_lds16(s, d);                                                         \
    gload_lds16(s + 262144, d + 8192);                                         \
  };                                                                           \
  auto STB = [&](int buf, int kt) {                                            \
    const char* s = Bg + kt * 64;                                              \
    char* d = lds + buf * 32768 + 16384 + t * 16;                              \
    gload_lds16(s, d);                                                         \
    gload_lds16(s + 262144, d + 8192);                                         \
  };                                                                           \
  STA(0, 0);                                                                   \
  STB(0, 0);                                                                   \
  VMCNT0();                                                                    \
  BAR();                                                                       \
  int cur = 0;                                                                 \
  for (int kt = 0; kt < 32; ++kt) {                                            \
    const int nx = cur ^ 1;                                                    \
    const char* ab = lds + cur * 32768;                                        \
    if (kt < 31) STA(nx, kt + 1);                                              \
    bf16x8 bfr[2][2];                                                          \
    _Pragma("unroll") for (int nh = 0; nh < 2; ++nh)                           \
    _Pragma("unroll") for (int j = 0; j < 2; ++j)                              \
      bfr[nh][j] = *(const bf16x8*)(ab + brb + (nh * 128 + j * 16) * 64);      \
    if (kt < 31) STB(nx, kt + 1);                                              \
    bf16x8 afr[4];                                                             \
    _Pragma("unroll") for (int i = 0; i < 4; ++i)                              \
      afr[i] = *(const bf16x8*)(ab + arb + (i * 16) * 64);                     \
    __builtin_amdgcn_s_setprio(1);                                             \
    _Pragma("unroll") for (int i = 0; i < 4; ++i)                              \
    _Pragma("unroll") for (int nh = 0; nh < 2; ++nh)                           \
    _Pragma("unroll") for (int j = 0; j < 2; ++j)                              \
      MFMA(acc[0][i][nh][j], afr[i], bfr[nh][j]);                              \
    __builtin_amdgcn_s_setprio(0);                                             \
    _Pragma("unroll") for (int i = 0; i < 4; ++i)                              \
      afr[i] = *(const bf16x8*)(ab + arb + ((128 + i * 16) * 64));             \
    __builtin_amdgcn_s_setprio(1);                                             \
    _Pragma("unroll") for (int i = 0; i < 4; ++i)                              \
    _Pragma("unroll") for (int nh = 0; nh < 2; ++nh)                           \
    _Pragma("unroll") for (int j = 0; j < 2; ++j)                              \
      MFMA(acc[1][i][nh][j], afr[i], bfr[nh][j]);                              \
    __builtin_amdgcn_s_setprio(0);                                             \
    if (kt < 31) VMCNT0();                                                     \
    BAR();                                                                     \
    cur = nx;                                                                  \
  }

// ---------------------------------------------------------------- GEMM1 ----
// h1 = relu(obs_bf16 @ W1 + b1)
__global__ __launch_bounds__(512, 4) void gemm1(
    const __bf16* __restrict__ obsb, const __bf16* __restrict__ BT1,
    const float* __restrict__ b1, __bf16* __restrict__ h1) {
  GEMM_KLOOP(obsb, BT1)
  // epilogue in two 64 KB halves; LDS scatter XOR-swizzled by accumulator g
  float b1v[2][2];
#pragma unroll
  for (int nh = 0; nh < 2; ++nh)
#pragma unroll
    for (int j = 0; j < 2; ++j)
      b1v[nh][j] = b1[nb * 256 + nh * 128 + wsc * 32 + j * 16 + l15];
  const int rr = t >> 2, qt = t & 3, grr = (rr >> 2) & 3;
#pragma unroll
  for (int mh = 0; mh < 2; ++mh) {
    __syncthreads();
#pragma unroll
    for (int i = 0; i < 4; ++i)
#pragma unroll
      for (int nh = 0; nh < 2; ++nh)
#pragma unroll
        for (int j = 0; j < 2; ++j)
#pragma unroll
          for (int reg = 0; reg < 4; ++reg) {
            float v = acc[mh][i][nh][j][reg] + b1v[nh][j];
            v = v > 0.f ? v : 0.f;
            const int Rl = wsr * 64 + i * 16 + g * 4 + reg;          // 0..127
            const int Cb = nh * 256 + wsc * 64 + j * 32 + l15 * 2;   // byte col
            *(__bf16*)(lds + Rl * 512 + (Cb ^ (g << 5))) = (__bf16)v;
          }
    __syncthreads();
    char* dp = (char*)h1 + (size_t)(mb * 256 + mh * 128 + rr) * 2048 +
               nb * 512 + qt * 128;
    const char* sp = lds + rr * 512;
#pragma unroll
    for (int q = 0; q < 8; ++q) {
      const int qe = (q + t) & 7;
      *(f32x4*)(dp + qe * 16) =
          *(const f32x4*)(sp + ((qt * 128 + qe * 16) ^ (grr << 5)));
    }
  }
}

// ---------------------------------------------------------------- GEMM2 ----
// h2 = relu(h1 @ W2 + b2); fused V4[nb][m] = sum_c h2[m][c]*W3[c]
__global__ __launch_bounds__(512, 4) void gemm2(
    const __bf16* __restrict__ h1, const __bf16* __restrict__ BT2,
    const float* __restrict__ b2, const float* __restrict__ W3,
    float* __restrict__ V4) {
  GEMM_KLOOP(h1, BT2)
  float b2v[2][2], w3v[2][2];
#pragma unroll
  for (int nh = 0; nh < 2; ++nh)
#pragma unroll
    for (int j = 0; j < 2; ++j) {
      const int C = nb * 256 + nh * 128 + wsc * 32 + j * 16 + l15;
      b2v[nh][j] = b2[C];
      w3v[nh][j] = W3[C];
    }
  float p[2][4][4];
#pragma unroll
  for (int mh = 0; mh < 2; ++mh)
#pragma unroll
    for (int i = 0; i < 4; ++i)
#pragma unroll
      for (int reg = 0; reg < 4; ++reg) {
        float s = 0.f;
#pragma unroll
        for (int nh = 0; nh < 2; ++nh)
#pragma unroll
          for (int j = 0; j < 2; ++j) {
            float v = acc[mh][i][nh][j][reg] + b2v[nh][j];
            v = v > 0.f ? v : 0.f;
            s += v * w3v[nh][j];
          }
        p[mh][i][reg] = s;
      }
#pragma unroll
  for (int d = 1; d < 16; d <<= 1)
#pragma unroll
    for (int mh = 0; mh < 2; ++mh)
#pragma unroll
      for (int i = 0; i < 4; ++i)
#pragma unroll
        for (int reg = 0; reg < 4; ++reg)
          p[mh][i][reg] += __shfl_xor(p[mh][i][reg], d, 64);
  float* vp = (float*)lds;  // [4 wsc][256 rows] = 4 KB
  if (l15 == 0) {
#pragma unroll
    for (int mh = 0; mh < 2; ++mh)
#pragma unroll
      for (int i = 0; i < 4; ++i)
#pragma unroll
        for (int reg = 0; reg < 4; ++reg)
          vp[wsc * 256 + mh * 128 + wsr * 64 + i * 16 + g * 4 + reg] =
              p[mh][i][reg];
  }
  __syncthreads();
  if (t < 256) {
    float s = vp[t] + vp[256 + t] + vp[512 + t] + vp[768 + t];
    V4[(size_t)nb * 65536 + mb * 256 + t] = s;
  }
}

// ---------------------------------------------------------------- final ----
__global__ __launch_bounds__(256) void final_kernel(const float* __restrict__ G,
                                                    const float* __restrict__ V4,
                                                    const float* __restrict__ b3,
                                                    float* __restrict__ out) {
  int i = blockIdx.x * 256 + threadIdx.x;
  out[i] = G[i] - (V4[i] + V4[65536 + i] + V4[131072 + i] + V4[196608 + i] + b3[0]);
}

extern "C" void kernel_launch(void* const* d_in, const int* in_sizes, int n_in,
                              void* d_out, int out_size, void* d_ws, size_t ws_size,
                              hipStream_t stream) {
  const float* rewards = (const float*)d_in[0];
  const float* obs = (const float*)d_in[1];
  const float* W1 = (const float*)d_in[2];
  const float* b1 = (const float*)d_in[3];
  const float* W2 = (const float*)d_in[4];
  const float* b2 = (const float*)d_in[5];
  const float* W3 = (const float*)d_in[6];
  const float* b3 = (const float*)d_in[7];
  float* out = (float*)d_out;

  char* ws = (char*)d_ws;
  __bf16* BT1 = (__bf16*)(ws);                    // 2 MiB
  __bf16* BT2 = (__bf16*)(ws + (2u << 20));       // 2 MiB
  float* V4 = (float*)(ws + (4u << 20));          // 1 MiB
  float* G = (float*)(ws + (5u << 20));           // 256 KiB
  __bf16* obsb = (__bf16*)(ws + (8u << 20));      // 128 MiB
  __bf16* h1 = (__bf16*)(ws + (136u << 20));      // 128 MiB

  hipFuncSetAttribute((const void*)gemm1,
                      hipFuncAttributeMaxDynamicSharedMemorySize, 65536);
  hipFuncSetAttribute((const void*)gemm2,
                      hipFuncAttributeMaxDynamicSharedMemorySize, 65536);

  mega_prep<<<1 + 2048 + 512, 1024, 0, stream>>>(rewards, G, obs, obsb, W1, W2,
                                                 BT1, BT2, 2048);
  gemm1<<<1024, 512, 65536, stream>>>(obsb, BT1, b1, h1);
  gemm2<<<1024, 512, 65536, stream>>>(h1, BT2, b2, W3, V4);
  final_kernel<<<256, 256, 0, stream>>>(G, V4, b3, out);
}

// Round 6
// 378.175 us; speedup vs baseline: 5.3268x; 5.3268x over previous
//
#include <hip/hip_runtime.h>

typedef __bf16 bf16x8 __attribute__((ext_vector_type(8)));
typedef __bf16 bf16x4 __attribute__((ext_vector_type(4)));
typedef float  f32x4  __attribute__((ext_vector_type(4)));

#define GAMMA 0.99f

__device__ __forceinline__ void gload_lds16(const void* g, void* l) {
  __builtin_amdgcn_global_load_lds(
      (const __attribute__((address_space(1))) void*)g,
      (__attribute__((address_space(3))) void*)l, 16, 0, 0);
}

#define VMCNT0() asm volatile("s_waitcnt vmcnt(0)" ::: "memory")
#define BAR() __builtin_amdgcn_s_barrier()
#define MFMA(d, a, b) d = __builtin_amdgcn_mfma_f32_16x16x32_bf16(a, b, d, 0, 0, 0)

// ------------------------------------------------- mega: scan + converts ----
// block 0            : discounted-return scan (1024 threads)
// blocks 1..nObs     : obs fp32 -> bf16 streaming convert
// blocks nObs+1..+512: W1/W2 transpose+cvt -> BT1/BT2 (4 subtiles per block)
__global__ __launch_bounds__(1024) void mega_prep(
    const float* __restrict__ rw, float* __restrict__ G,
    const float* __restrict__ obs, __bf16* __restrict__ obsb,
    const float* __restrict__ W1, const float* __restrict__ W2,
    __bf16* __restrict__ BT1, __bf16* __restrict__ BT2, int nObs) {
  __shared__ float smem[4224];
  const int blk = blockIdx.x;
  const int t = threadIdx.x;
  if (blk == 0) {
    // ---- scan ----
    float* sv = smem;
    const float4* rp = (const float4*)(rw + t * 64);
    float4 lv[16];
#pragma unroll
    for (int i = 0; i < 16; ++i) lv[i] = rp[i];
    float loc[64];
#pragma unroll
    for (int i = 0; i < 16; ++i) {
      loc[4 * i + 0] = lv[i].x; loc[4 * i + 1] = lv[i].y;
      loc[4 * i + 2] = lv[i].z; loc[4 * i + 3] = lv[i].w;
    }
    float g = 0.f;
#pragma unroll
    for (int j = 63; j >= 0; --j) { g = loc[j] + GAMMA * g; loc[j] = g; }
    sv[t] = g;
    float W = GAMMA;
#pragma unroll
    for (int i = 0; i < 6; ++i) W *= W;  // gamma^64
    float v = g;
    for (int s = 1; s < 1024; s <<= 1) {
      __syncthreads();
      float o = (t + s < 1024) ? sv[t + s] : 0.f;
      __syncthreads();
      v += W * o;
      sv[t] = v;
      W *= W;
    }
    __syncthreads();
    const float nxt = (t < 1023) ? sv[t + 1] : 0.f;
    float pw = GAMMA;
#pragma unroll
    for (int j = 63; j >= 0; --j) {
      G[t * 64 + j] = loc[j] + pw * nxt;
      pw *= GAMMA;
    }
  } else if (blk <= nObs) {
    // ---- obs convert: 32768 elems per block ----
    const size_t base = (size_t)(blk - 1) * 32768 + (size_t)t * 8;
#pragma unroll
    for (int it = 0; it < 4; ++it) {
      const size_t e = base + (size_t)it * 8192;
      float4 u0 = *(const float4*)(obs + e);
      float4 u1 = *(const float4*)(obs + e + 4);
      bf16x8 o = {(__bf16)u0.x, (__bf16)u0.y, (__bf16)u0.z, (__bf16)u0.w,
                  (__bf16)u1.x, (__bf16)u1.y, (__bf16)u1.z, (__bf16)u1.w};
      *(bf16x8*)(obsb + e) = o;
    }
  } else {
    // ---- W transpose+cvt: 4 subtiles of 32x32 per block ----
    const int sub = t >> 8, tt = t & 255;
    const int wi = (blk - nObs - 1) * 4 + sub;  // 0..2047
    const float* W = (wi >= 1024) ? W2 : W1;
    __bf16* O = (wi >= 1024) ? BT2 : BT1;
    const int tile = wi & 1023;
    const int ti = tile >> 5, tj = tile & 31;
    float* s = smem + sub * 1056;  // [32][33]
    const int rr = tt >> 3, c4 = (tt & 7) * 4;
    float4 v = *(const float4*)(W + (size_t)(ti * 32 + rr) * 1024 + tj * 32 + c4);
    s[rr * 33 + c4 + 0] = v.x; s[rr * 33 + c4 + 1] = v.y;
    s[rr * 33 + c4 + 2] = v.z; s[rr * 33 + c4 + 3] = v.w;
    __syncthreads();
    bf16x4 o = {(__bf16)s[(c4 + 0) * 33 + rr], (__bf16)s[(c4 + 1) * 33 + rr],
                (__bf16)s[(c4 + 2) * 33 + rr], (__bf16)s[(c4 + 3) * 33 + rr]};
    *(bf16x4*)(O + (size_t)(tj * 32 + rr) * 1024 + ti * 32 + c4) = o;
  }
}

// ---------------------------------------------------------------------------
// GEMM: BM=BN=256, BK=32, 512 threads = 8 waves (wsr 2 x wsc 4), 2 blocks/CU.
// LDS 64 KB: buf{0,1} x { A [256r][32k] , B [256n][32k] } bf16, 64-B rows.
// Row r holds 4 16-B chunks; global chunk g stored at slot g ^ ((r>>1)&3)
// (conflict-free for both the linear gload_lds staging and the frag reads).
// One barrier + one vmcnt(0) per K-tile; cross-block overlap hides drains.
// NOTE launch_bounds second arg MUST be 2 (not 4): 4 caps VGPR at 64 and
// spills the 64-reg accumulator to scratch (R5: 4.7 GB traffic, 5% MfmaUtil).
// ---------------------------------------------------------------------------
#define GEMM_KLOOP(APTR, BPTR)                                                 \
  extern __shared__ char lds[];                                                \
  const int t = threadIdx.x, lane = t & 63, w = t >> 6;                        \
  const int wsr = w >> 2, wsc = w & 3, g = lane >> 4, l15 = lane & 15;         \
  const int bid = blockIdx.x;                                                  \
  const int mb = (bid & 7) * 32 + ((bid >> 3) >> 2);                           \
  const int nb = (bid >> 3) & 3;                                               \
  const size_t stg_off =                                                       \
      (size_t)(t >> 2) * 2048 + (size_t)(((t & 3) ^ ((t >> 3) & 3)) * 16);     \
  const char* Ag = (const char*)(APTR) + (size_t)mb * 524288 + stg_off;        \
  const char* Bg = (const char*)(BPTR) + (size_t)nb * 524288 + stg_off;        \
  const int csw = (g ^ ((l15 >> 1) & 3)) << 4;                                 \
  const int arb = (wsr * 64 + l15) * 64 + csw;                                 \
  const int brb = (wsc * 32 + l15) * 64 + csw + 16384;                         \
  f32x4 acc[2][4][2][2];                                                       \
  const f32x4 zero = {0.f, 0.f, 0.f, 0.f};                                     \
  _Pragma("unroll") for (int a_ = 0; a_ < 2; ++a_)                             \
  _Pragma("unroll") for (int b_ = 0; b_ < 4; ++b_)                             \
  _Pragma("unroll") for (int c_ = 0; c_ < 2; ++c_)                             \
  _Pragma("unroll") for (int d_ = 0; d_ < 2; ++d_)                             \
    acc[a_][b_][c_][d_] = zero;                                                \
  auto STA = [&](int buf, int kt) {                                            \
    const char* s = Ag + kt * 64;                                              \
    char* d = lds + buf * 32768 + t * 16;                                      \
    gload_lds16(s, d);                                                         \
    gload_lds16(s + 262144, d + 8192);                                         \
  };                                                                           \
  auto STB = [&](int buf, int kt) {                                            \
    const char* s = Bg + kt * 64;                                              \
    char* d = lds + buf * 32768 + 16384 + t * 16;                              \
    gload_lds16(s, d);                                                         \
    gload_lds16(s + 262144, d + 8192);                                         \
  };                                                                           \
  STA(0, 0);                                                                   \
  STB(0, 0);                                                                   \
  VMCNT0();                                                                    \
  BAR();                                                                       \
  int cur = 0;                                                                 \
  for (int kt = 0; kt < 32; ++kt) {                                            \
    const int nx = cur ^ 1;                                                    \
    const char* ab = lds + cur * 32768;                                        \
    if (kt < 31) STA(nx, kt + 1);                                              \
    bf16x8 bfr[2][2];                                                          \
    _Pragma("unroll") for (int nh = 0; nh < 2; ++nh)                           \
    _Pragma("unroll") for (int j = 0; j < 2; ++j)                              \
      bfr[nh][j] = *(const bf16x8*)(ab + brb + (nh * 128 + j * 16) * 64);      \
    if (kt < 31) STB(nx, kt + 1);                                              \
    bf16x8 afr[4];                                                             \
    _Pragma("unroll") for (int i = 0; i < 4; ++i)                              \
      afr[i] = *(const bf16x8*)(ab + arb + (i * 16) * 64);                     \
    __builtin_amdgcn_s_setprio(1);                                             \
    _Pragma("unroll") for (int i = 0; i < 4; ++i)                              \
    _Pragma("unroll") for (int nh = 0; nh < 2; ++nh)                           \
    _Pragma("unroll") for (int j = 0; j < 2; ++j)                              \
      MFMA(acc[0][i][nh][j], afr[i], bfr[nh][j]);                              \
    __builtin_amdgcn_s_setprio(0);                                             \
    _Pragma("unroll") for (int i = 0; i < 4; ++i)                              \
      afr[i] = *(const bf16x8*)(ab + arb + ((128 + i * 16) * 64));             \
    __builtin_amdgcn_s_setprio(1);                                             \
    _Pragma("unroll") for (int i = 0; i < 4; ++i)                              \
    _Pragma("unroll") for (int nh = 0; nh < 2; ++nh)                           \
    _Pragma("unroll") for (int j = 0; j < 2; ++j)                              \
      MFMA(acc[1][i][nh][j], afr[i], bfr[nh][j]);                              \
    __builtin_amdgcn_s_setprio(0);                                             \
    if (kt < 31) VMCNT0();                                                     \
    BAR();                                                                     \
    cur = nx;                                                                  \
  }

// ---------------------------------------------------------------- GEMM1 ----
// h1 = relu(obs_bf16 @ W1 + b1)
__global__ __launch_bounds__(512, 2) void gemm1(
    const __bf16* __restrict__ obsb, const __bf16* __restrict__ BT1,
    const float* __restrict__ b1, __bf16* __restrict__ h1) {
  GEMM_KLOOP(obsb, BT1)
  // epilogue in two 64 KB halves; LDS scatter XOR-swizzled by accumulator g
  float b1v[2][2];
#pragma unroll
  for (int nh = 0; nh < 2; ++nh)
#pragma unroll
    for (int j = 0; j < 2; ++j)
      b1v[nh][j] = b1[nb * 256 + nh * 128 + wsc * 32 + j * 16 + l15];
  const int rr = t >> 2, qt = t & 3, grr = (rr >> 2) & 3;
#pragma unroll
  for (int mh = 0; mh < 2; ++mh) {
    __syncthreads();
#pragma unroll
    for (int i = 0; i < 4; ++i)
#pragma unroll
      for (int nh = 0; nh < 2; ++nh)
#pragma unroll
        for (int j = 0; j < 2; ++j)
#pragma unroll
          for (int reg = 0; reg < 4; ++reg) {
            float v = acc[mh][i][nh][j][reg] + b1v[nh][j];
            v = v > 0.f ? v : 0.f;
            const int Rl = wsr * 64 + i * 16 + g * 4 + reg;          // 0..127
            const int Cb = nh * 256 + wsc * 64 + j * 32 + l15 * 2;   // byte col
            *(__bf16*)(lds + Rl * 512 + (Cb ^ (g << 5))) = (__bf16)v;
          }
    __syncthreads();
    char* dp = (char*)h1 + (size_t)(mb * 256 + mh * 128 + rr) * 2048 +
               nb * 512 + qt * 128;
    const char* sp = lds + rr * 512;
#pragma unroll
    for (int q = 0; q < 8; ++q) {
      const int qe = (q + t) & 7;
      *(f32x4*)(dp + qe * 16) =
          *(const f32x4*)(sp + ((qt * 128 + qe * 16) ^ (grr << 5)));
    }
  }
}

// ---------------------------------------------------------------- GEMM2 ----
// h2 = relu(h1 @ W2 + b2); fused V4[nb][m] = sum_c h2[m][c]*W3[c]
__global__ __launch_bounds__(512, 2) void gemm2(
    const __bf16* __restrict__ h1, const __bf16* __restrict__ BT2,
    const float* __restrict__ b2, const float* __restrict__ W3,
    float* __restrict__ V4) {
  GEMM_KLOOP(h1, BT2)
  float b2v[2][2], w3v[2][2];
#pragma unroll
  for (int nh = 0; nh < 2; ++nh)
#pragma unroll
    for (int j = 0; j < 2; ++j) {
      const int C = nb * 256 + nh * 128 + wsc * 32 + j * 16 + l15;
      b2v[nh][j] = b2[C];
      w3v[nh][j] = W3[C];
    }
  float p[2][4][4];
#pragma unroll
  for (int mh = 0; mh < 2; ++mh)
#pragma unroll
    for (int i = 0; i < 4; ++i)
#pragma unroll
      for (int reg = 0; reg < 4; ++reg) {
        float s = 0.f;
#pragma unroll
        for (int nh = 0; nh < 2; ++nh)
#pragma unroll
          for (int j = 0; j < 2; ++j) {
            float v = acc[mh][i][nh][j][reg] + b2v[nh][j];
            v = v > 0.f ? v : 0.f;
            s += v * w3v[nh][j];
          }
        p[mh][i][reg] = s;
      }
#pragma unroll
  for (int d = 1; d < 16; d <<= 1)
#pragma unroll
    for (int mh = 0; mh < 2; ++mh)
#pragma unroll
      for (int i = 0; i < 4; ++i)
#pragma unroll
        for (int reg = 0; reg < 4; ++reg)
          p[mh][i][reg] += __shfl_xor(p[mh][i][reg], d, 64);
  float* vp = (float*)lds;  // [4 wsc][256 rows] = 4 KB
  if (l15 == 0) {
#pragma unroll
    for (int mh = 0; mh < 2; ++mh)
#pragma unroll
      for (int i = 0; i < 4; ++i)
#pragma unroll
        for (int reg = 0; reg < 4; ++reg)
          vp[wsc * 256 + mh * 128 + wsr * 64 + i * 16 + g * 4 + reg] =
              p[mh][i][reg];
  }
  __syncthreads();
  if (t < 256) {
    float s = vp[t] + vp[256 + t] + vp[512 + t] + vp[768 + t];
    V4[(size_t)nb * 65536 + mb * 256 + t] = s;
  }
}

// ---------------------------------------------------------------- final ----
__global__ __launch_bounds__(256) void final_kernel(const float* __restrict__ G,
                                                    const float* __restrict__ V4,
                                                    const float* __restrict__ b3,
                                                    float* __restrict__ out) {
  int i = blockIdx.x * 256 + threadIdx.x;
  out[i] = G[i] - (V4[i] + V4[65536 + i] + V4[131072 + i] + V4[196608 + i] + b3[0]);
}

extern "C" void kernel_launch(void* const* d_in, const int* in_sizes, int n_in,
                              void* d_out, int out_size, void* d_ws, size_t ws_size,
                              hipStream_t stream) {
  const float* rewards = (const float*)d_in[0];
  const float* obs = (const float*)d_in[1];
  const float* W1 = (const float*)d_in[2];
  const float* b1 = (const float*)d_in[3];
  const float* W2 = (const float*)d_in[4];
  const float* b2 = (const float*)d_in[5];
  const float* W3 = (const float*)d_in[6];
  const float* b3 = (const float*)d_in[7];
  float* out = (float*)d_out;

  char* ws = (char*)d_ws;
  __bf16* BT1 = (__bf16*)(ws);                    // 2 MiB
  __bf16* BT2 = (__bf16*)(ws + (2u << 20));       // 2 MiB
  float* V4 = (float*)(ws + (4u << 20));          // 1 MiB
  float* G = (float*)(ws + (5u << 20));           // 256 KiB
  __bf16* obsb = (__bf16*)(ws + (8u << 20));      // 128 MiB
  __bf16* h1 = (__bf16*)(ws + (136u << 20));      // 128 MiB

  hipFuncSetAttribute((const void*)gemm1,
                      hipFuncAttributeMaxDynamicSharedMemorySize, 65536);
  hipFuncSetAttribute((const void*)gemm2,
                      hipFuncAttributeMaxDynamicSharedMemorySize, 65536);

  mega_prep<<<1 + 2048 + 512, 1024, 0, stream>>>(rewards, G, obs, obsb, W1, W2,
                                                 BT1, BT2, 2048);
  gemm1<<<1024, 512, 65536, stream>>>(obsb, BT1, b1, h1);
  gemm2<<<1024, 512, 65536, stream>>>(h1, BT2, b2, W3, V4);
  final_kernel<<<256, 256, 0, stream>>>(G, V4, b3, out);
}

// Round 7
// 357.707 us; speedup vs baseline: 5.6316x; 1.0572x over previous
//
#include <hip/hip_runtime.h>

typedef __bf16 bf16x8 __attribute__((ext_vector_type(8)));
typedef __bf16 bf16x4 __attribute__((ext_vector_type(4)));
typedef float  f32x4  __attribute__((ext_vector_type(4)));

#define GAMMA 0.99f

__device__ __forceinline__ void gload_lds16(const void* g, void* l) {
  __builtin_amdgcn_global_load_lds(
      (const __attribute__((address_space(1))) void*)g,
      (__attribute__((address_space(3))) void*)l, 16, 0, 0);
}

#define VMCNT0() asm volatile("s_waitcnt vmcnt(0)" ::: "memory")
#define BAR() __builtin_amdgcn_s_barrier()
#define MFMA(d, a, b) d = __builtin_amdgcn_mfma_f32_16x16x32_bf16(a, b, d, 0, 0, 0)

// ------------------------------------------------- mega: scan + converts ----
__global__ __launch_bounds__(1024) void mega_prep(
    const float* __restrict__ rw, float* __restrict__ G,
    const float* __restrict__ obs, __bf16* __restrict__ obsb,
    const float* __restrict__ W1, const float* __restrict__ W2,
    __bf16* __restrict__ BT1, __bf16* __restrict__ BT2, int nObs) {
  __shared__ float smem[4224];
  const int blk = blockIdx.x;
  const int t = threadIdx.x;
  if (blk == 0) {
    // ---- scan ----
    float* sv = smem;
    const float4* rp = (const float4*)(rw + t * 64);
    float4 lv[16];
#pragma unroll
    for (int i = 0; i < 16; ++i) lv[i] = rp[i];
    float loc[64];
#pragma unroll
    for (int i = 0; i < 16; ++i) {
      loc[4 * i + 0] = lv[i].x; loc[4 * i + 1] = lv[i].y;
      loc[4 * i + 2] = lv[i].z; loc[4 * i + 3] = lv[i].w;
    }
    float g = 0.f;
#pragma unroll
    for (int j = 63; j >= 0; --j) { g = loc[j] + GAMMA * g; loc[j] = g; }
    sv[t] = g;
    float W = GAMMA;
#pragma unroll
    for (int i = 0; i < 6; ++i) W *= W;  // gamma^64
    float v = g;
    for (int s = 1; s < 1024; s <<= 1) {
      __syncthreads();
      float o = (t + s < 1024) ? sv[t + s] : 0.f;
      __syncthreads();
      v += W * o;
      sv[t] = v;
      W *= W;
    }
    __syncthreads();
    const float nxt = (t < 1023) ? sv[t + 1] : 0.f;
    float pw = GAMMA;
#pragma unroll
    for (int j = 63; j >= 0; --j) {
      G[t * 64 + j] = loc[j] + pw * nxt;
      pw *= GAMMA;
    }
  } else if (blk <= nObs) {
    // ---- obs convert: 32768 elems per block ----
    const size_t base = (size_t)(blk - 1) * 32768 + (size_t)t * 8;
#pragma unroll
    for (int it = 0; it < 4; ++it) {
      const size_t e = base + (size_t)it * 8192;
      float4 u0 = *(const float4*)(obs + e);
      float4 u1 = *(const float4*)(obs + e + 4);
      bf16x8 o = {(__bf16)u0.x, (__bf16)u0.y, (__bf16)u0.z, (__bf16)u0.w,
                  (__bf16)u1.x, (__bf16)u1.y, (__bf16)u1.z, (__bf16)u1.w};
      *(bf16x8*)(obsb + e) = o;
    }
  } else {
    // ---- W transpose+cvt: 4 subtiles of 32x32 per block ----
    const int sub = t >> 8, tt = t & 255;
    const int wi = (blk - nObs - 1) * 4 + sub;  // 0..2047
    const float* W = (wi >= 1024) ? W2 : W1;
    __bf16* O = (wi >= 1024) ? BT2 : BT1;
    const int tile = wi & 1023;
    const int ti = tile >> 5, tj = tile & 31;
    float* s = smem + sub * 1056;  // [32][33]
    const int rr = tt >> 3, c4 = (tt & 7) * 4;
    float4 v = *(const float4*)(W + (size_t)(ti * 32 + rr) * 1024 + tj * 32 + c4);
    s[rr * 33 + c4 + 0] = v.x; s[rr * 33 + c4 + 1] = v.y;
    s[rr * 33 + c4 + 2] = v.z; s[rr * 33 + c4 + 3] = v.w;
    __syncthreads();
    bf16x4 o = {(__bf16)s[(c4 + 0) * 33 + rr], (__bf16)s[(c4 + 1) * 33 + rr],
                (__bf16)s[(c4 + 2) * 33 + rr], (__bf16)s[(c4 + 3) * 33 + rr]};
    *(bf16x4*)(O + (size_t)(tj * 32 + rr) * 1024 + ti * 32 + c4) = o;
  }
}

// ---------------------------------------------------------------------------
// GEMM: BM=BN=256, BK=32, 512 threads = 8 waves (wsr 2 x wsc 4).
// LDS 64 KB: buf{0,1} x { A [256r][32k] , B [256n][32k] } bf16, 64-B rows.
// Row r: 4 16-B chunks; chunk g at slot g ^ ((r>>1)&3) (conflict-free both
// for linear gload_lds staging and frag reads).
// SWAPPED MFMA: D = B_frag x A_frag  =>  acc[reg] = 4 consecutive n-cols of
// one m-row (m = l15 + 16i [+64wsr+128mh], n = g*4+reg + 16j + 32wsc + 128nh)
// -> epilogue stores bf16x4 straight to global, no LDS round-trip.
// launch_bounds second arg MUST be 2: (512,4) caps VGPR at 64 -> acc spills.
// ---------------------------------------------------------------------------
#define GEMM_KLOOP(APTR, BPTR)                                                 \
  extern __shared__ char lds[];                                                \
  const int t = threadIdx.x, lane = t & 63, w = t >> 6;                        \
  const int wsr = w >> 2, wsc = w & 3, g = lane >> 4, l15 = lane & 15;         \
  const int bid = blockIdx.x;                                                  \
  const int mb = (bid & 7) * 32 + ((bid >> 3) >> 2);                           \
  const int nb = (bid >> 3) & 3;                                               \
  const size_t stg_off =                                                       \
      (size_t)(t >> 2) * 2048 + (size_t)(((t & 3) ^ ((t >> 3) & 3)) * 16);     \
  const char* Ag = (const char*)(APTR) + (size_t)mb * 524288 + stg_off;        \
  const char* Bg = (const char*)(BPTR) + (size_t)nb * 524288 + stg_off;        \
  const int csw = (g ^ ((l15 >> 1) & 3)) << 4;                                 \
  const int arb = (wsr * 64 + l15) * 64 + csw;                                 \
  const int brb = (wsc * 32 + l15) * 64 + csw + 16384;                         \
  f32x4 acc[2][4][2][2];                                                       \
  const f32x4 zero = {0.f, 0.f, 0.f, 0.f};                                     \
  _Pragma("unroll") for (int a_ = 0; a_ < 2; ++a_)                             \
  _Pragma("unroll") for (int b_ = 0; b_ < 4; ++b_)                             \
  _Pragma("unroll") for (int c_ = 0; c_ < 2; ++c_)                             \
  _Pragma("unroll") for (int d_ = 0; d_ < 2; ++d_)                             \
    acc[a_][b_][c_][d_] = zero;                                                \
  auto STA = [&](int buf, int kt) {                                            \
    const char* s = Ag + kt * 64;                                              \
    char* d = lds + buf * 32768 + t * 16;                                      \
    gload_lds16(s, d);                                                         \
    gload_lds16(s + 262144, d + 8192);                                         \
  };                                                                           \
  auto STB = [&](int buf, int kt) {                                            \
    const char* s = Bg + kt * 64;                                              \
    char* d = lds + buf * 32768 + 16384 + t * 16;                              \
    gload_lds16(s, d);                                                         \
    gload_lds16(s + 262144, d + 8192);                                         \
  };                                                                           \
  STA(0, 0);                                                                   \
  STB(0, 0);                                                                   \
  VMCNT0();                                                                    \
  BAR();                                                                       \
  int cur = 0;                                                                 \
  for (int kt = 0; kt < 32; ++kt) {                                            \
    const int nx = cur ^ 1;                                                    \
    const char* ab = lds + cur * 32768;                                        \
    if (kt < 31) STA(nx, kt + 1);                                              \
    bf16x8 bfr[2][2];                                                          \
    _Pragma("unroll") for (int nh = 0; nh < 2; ++nh)                           \
    _Pragma("unroll") for (int j = 0; j < 2; ++j)                              \
      bfr[nh][j] = *(const bf16x8*)(ab + brb + (nh * 128 + j * 16) * 64);      \
    if (kt < 31) STB(nx, kt + 1);                                              \
    bf16x8 afr[4];                                                             \
    _Pragma("unroll") for (int i = 0; i < 4; ++i)                              \
      afr[i] = *(const bf16x8*)(ab + arb + (i * 16) * 64);                     \
    __builtin_amdgcn_s_setprio(1);                                             \
    _Pragma("unroll") for (int i = 0; i < 4; ++i)                              \
    _Pragma("unroll") for (int nh = 0; nh < 2; ++nh)                           \
    _Pragma("unroll") for (int j = 0; j < 2; ++j)                              \
      MFMA(acc[0][i][nh][j], bfr[nh][j], afr[i]);                              \
    __builtin_amdgcn_s_setprio(0);                                             \
    _Pragma("unroll") for (int i = 0; i < 4; ++i)                              \
      afr[i] = *(const bf16x8*)(ab + arb + ((128 + i * 16) * 64));             \
    __builtin_amdgcn_s_setprio(1);                                             \
    _Pragma("unroll") for (int i = 0; i < 4; ++i)                              \
    _Pragma("unroll") for (int nh = 0; nh < 2; ++nh)                           \
    _Pragma("unroll") for (int j = 0; j < 2; ++j)                              \
      MFMA(acc[1][i][nh][j], bfr[nh][j], afr[i]);                              \
    __builtin_amdgcn_s_setprio(0);                                             \
    if (kt < 31) VMCNT0();                                                     \
    BAR();                                                                     \
    cur = nx;                                                                  \
  }

// ---------------------------------------------------------------- GEMM1 ----
// h1 = relu(obs_bf16 @ W1 + b1); direct bf16x4 stores (no LDS epilogue)
__global__ __launch_bounds__(512, 2) void gemm1(
    const __bf16* __restrict__ obsb, const __bf16* __restrict__ BT1,
    const float* __restrict__ b1, __bf16* __restrict__ h1) {
  GEMM_KLOOP(obsb, BT1)
  f32x4 b1q[2][2];
#pragma unroll
  for (int nh = 0; nh < 2; ++nh)
#pragma unroll
    for (int j = 0; j < 2; ++j)
      b1q[nh][j] =
          *(const f32x4*)(b1 + nb * 256 + nh * 128 + wsc * 32 + j * 16 + g * 4);
#pragma unroll
  for (int mh = 0; mh < 2; ++mh)
#pragma unroll
    for (int i = 0; i < 4; ++i) {
      const size_t mrow = (size_t)(mb * 256 + mh * 128 + wsr * 64 + i * 16 + l15);
#pragma unroll
      for (int nh = 0; nh < 2; ++nh)
#pragma unroll
        for (int j = 0; j < 2; ++j) {
          f32x4 v = acc[mh][i][nh][j];
          v.x += b1q[nh][j].x; v.y += b1q[nh][j].y;
          v.z += b1q[nh][j].z; v.w += b1q[nh][j].w;
          v.x = v.x > 0.f ? v.x : 0.f;
          v.y = v.y > 0.f ? v.y : 0.f;
          v.z = v.z > 0.f ? v.z : 0.f;
          v.w = v.w > 0.f ? v.w : 0.f;
          bf16x4 o = {(__bf16)v.x, (__bf16)v.y, (__bf16)v.z, (__bf16)v.w};
          *(bf16x4*)(h1 + mrow * 1024 + nb * 256 + nh * 128 + wsc * 32 +
                     j * 16 + g * 4) = o;
        }
    }
}

// ---------------------------------------------------------------- GEMM2 ----
// h2 = relu(h1 @ W2 + b2); fused V4[nb][m] = sum_c h2[m][c]*W3[c]
__global__ __launch_bounds__(512, 2) void gemm2(
    const __bf16* __restrict__ h1, const __bf16* __restrict__ BT2,
    const float* __restrict__ b2, const float* __restrict__ W3,
    float* __restrict__ V4) {
  GEMM_KLOOP(h1, BT2)
  f32x4 b2q[2][2], w3q[2][2];
#pragma unroll
  for (int nh = 0; nh < 2; ++nh)
#pragma unroll
    for (int j = 0; j < 2; ++j) {
      const int C = nb * 256 + nh * 128 + wsc * 32 + j * 16 + g * 4;
      b2q[nh][j] = *(const f32x4*)(b2 + C);
      w3q[nh][j] = *(const f32x4*)(W3 + C);
    }
  float p[2][4];
#pragma unroll
  for (int mh = 0; mh < 2; ++mh)
#pragma unroll
    for (int i = 0; i < 4; ++i) {
      float s = 0.f;
#pragma unroll
      for (int nh = 0; nh < 2; ++nh)
#pragma unroll
        for (int j = 0; j < 2; ++j) {
          f32x4 v = acc[mh][i][nh][j];
          v.x += b2q[nh][j].x; v.y += b2q[nh][j].y;
          v.z += b2q[nh][j].z; v.w += b2q[nh][j].w;
          v.x = v.x > 0.f ? v.x : 0.f;
          v.y = v.y > 0.f ? v.y : 0.f;
          v.z = v.z > 0.f ? v.z : 0.f;
          v.w = v.w > 0.f ? v.w : 0.f;
          s += v.x * w3q[nh][j].x + v.y * w3q[nh][j].y +
               v.z * w3q[nh][j].z + v.w * w3q[nh][j].w;
        }
      p[mh][i] = s;
    }
  // reduce over g-groups (lanes ^16, ^32): lanes now all hold row-partial
#pragma unroll
  for (int mh = 0; mh < 2; ++mh)
#pragma unroll
    for (int i = 0; i < 4; ++i) {
      p[mh][i] += __shfl_xor(p[mh][i], 16, 64);
      p[mh][i] += __shfl_xor(p[mh][i], 32, 64);
    }
  float* vp = (float*)lds;  // [4 wsc][256 rows] = 4 KB
  if (g == 0) {
#pragma unroll
    for (int mh = 0; mh < 2; ++mh)
#pragma unroll
      for (int i = 0; i < 4; ++i)
        vp[wsc * 256 + mh * 128 + wsr * 64 + i * 16 + l15] = p[mh][i];
  }
  __syncthreads();
  if (t < 256) {
    float s = vp[t] + vp[256 + t] + vp[512 + t] + vp[768 + t];
    V4[(size_t)nb * 65536 + mb * 256 + t] = s;
  }
}

// ---------------------------------------------------------------- final ----
__global__ __launch_bounds__(256) void final_kernel(const float* __restrict__ G,
                                                    const float* __restrict__ V4,
                                                    const float* __restrict__ b3,
                                                    float* __restrict__ out) {
  int i = blockIdx.x * 256 + threadIdx.x;
  out[i] = G[i] - (V4[i] + V4[65536 + i] + V4[131072 + i] + V4[196608 + i] + b3[0]);
}

extern "C" void kernel_launch(void* const* d_in, const int* in_sizes, int n_in,
                              void* d_out, int out_size, void* d_ws, size_t ws_size,
                              hipStream_t stream) {
  const float* rewards = (const float*)d_in[0];
  const float* obs = (const float*)d_in[1];
  const float* W1 = (const float*)d_in[2];
  const float* b1 = (const float*)d_in[3];
  const float* W2 = (const float*)d_in[4];
  const float* b2 = (const float*)d_in[5];
  const float* W3 = (const float*)d_in[6];
  const float* b3 = (const float*)d_in[7];
  float* out = (float*)d_out;

  char* ws = (char*)d_ws;
  __bf16* BT1 = (__bf16*)(ws);                    // 2 MiB
  __bf16* BT2 = (__bf16*)(ws + (2u << 20));       // 2 MiB
  float* V4 = (float*)(ws + (4u << 20));          // 1 MiB
  float* G = (float*)(ws + (5u << 20));           // 256 KiB
  __bf16* obsb = (__bf16*)(ws + (8u << 20));      // 128 MiB
  __bf16* h1 = (__bf16*)(ws + (136u << 20));      // 128 MiB

  hipFuncSetAttribute((const void*)gemm1,
                      hipFuncAttributeMaxDynamicSharedMemorySize, 65536);
  hipFuncSetAttribute((const void*)gemm2,
                      hipFuncAttributeMaxDynamicSharedMemorySize, 65536);

  mega_prep<<<1 + 2048 + 512, 1024, 0, stream>>>(rewards, G, obs, obsb, W1, W2,
                                                 BT1, BT2, 2048);
  gemm1<<<1024, 512, 65536, stream>>>(obsb, BT1, b1, h1);
  gemm2<<<1024, 512, 65536, stream>>>(h1, BT2, b2, W3, V4);
  final_kernel<<<256, 256, 0, stream>>>(G, V4, b3, out);
}